// Round 8
// baseline (302.292 us; speedup 1.0000x reference)
//
#include <hip/hip_runtime.h>

#define NB 8
#define NS 4
#define NN 8192
#define NM 50
#define K10 10
#define COST_THRESH 50.0f
#define LOSS_BLOCKS 256
#define MPB 2                  // gt's per block
#define CAP 1024
#define TOTAL (NB * NS * NN)
#define TT 512                 // topk threads
#define ELEMS (NN / TT)        // 16 per thread

__device__ __forceinline__ bool lexless(float d1, int i1, float d2, int i2) {
  // matches jax.lax.top_k ordering on -dist: (dist asc, index asc)
  return (d1 < d2) || (d1 == d2 && i1 < i2);
}

// Clear assign + scalars only.
__global__ void __launch_bounds__(256) prep_kernel(
    int* __restrict__ assign, float* __restrict__ acc,
    int* __restrict__ bs_unm, int* __restrict__ done) {
  int i = blockIdx.x * blockDim.x + threadIdx.x;
  for (int j = i; j < TOTAL; j += gridDim.x * blockDim.x) assign[j] = -1;
  if (i == 0) { acc[0] = 0.0f; *done = 0; }
  if (i >= 64 && i < 64 + NB * NS) bs_unm[i - 64] = 0;
}

// One block per (b, s, m-pair): exact top-10 for TWO gt's. Bound found by
// block-uniform bisection with register compares (NO LDS-atomic histogram).
__global__ void __launch_bounds__(TT) topk_kernel(
    const float* __restrict__ pred_boxes, const float* __restrict__ pred_scores,
    const float* __restrict__ gt_boxes, const int* __restrict__ n_gt,
    int* __restrict__ assign, float* __restrict__ per_gt_sum,
    int* __restrict__ bs_unm) {
  const int blk = blockIdx.x;           // bs * (NM/MPB) + mpair
  const int mp = blk % (NM / MPB);
  const int bs = blk / (NM / MPB);
  const int b = bs / NS;
  const int m0 = mp * MPB;
  const int t = threadIdx.x;
  const int wave = t >> 6;
  const int lane = t & 63;

  __shared__ float scd[MPB][CAP];           // 8 KB
  __shared__ int sci[MPB][CAP];             // 8 KB
  __shared__ float sred[4][8];              // {min0,max0,min1,max1} x 8 waves
  __shared__ float sbb[MPB][2];             // bmin, bmax per m
  __shared__ int scount[2][8][MPB];         // bisection partial counts (dbuf)
  __shared__ int scnt[MPB];
  __shared__ float soutd[MPB][K10];
  __shared__ int souti[MPB][K10];

  if (t < MPB) scnt[t] = 0;

  const float g0x = gt_boxes[(b * NM + m0) * 7 + 0];
  const float g0y = gt_boxes[(b * NM + m0) * 7 + 1];
  const float g0z = gt_boxes[(b * NM + m0) * 7 + 2];
  const float g1x = gt_boxes[(b * NM + m0 + 1) * 7 + 0];
  const float g1y = gt_boxes[(b * NM + m0 + 1) * 7 + 1];
  const float g1z = gt_boxes[(b * NM + m0 + 1) * 7 + 2];
  const int ngt = n_gt[b];

  // P1: shared loads, d^2 for both m's into registers; per-m min/max
  const float* pb = pred_boxes + (size_t)bs * NN * 7;
  float d2a[ELEMS], d2b[ELEMS];
  float lmin0 = INFINITY, lmax0 = 0.0f, lmin1 = INFINITY, lmax1 = 0.0f;
#pragma unroll
  for (int e = 0; e < ELEMS; e++) {
    int n = t + e * TT;
    float x = pb[n * 7 + 0];
    float y = pb[n * 7 + 1];
    float z = pb[n * 7 + 2];
    float dx = x - g0x, dy = y - g0y, dz = z - g0z;
    float d2 = dx * dx + dy * dy + dz * dz;
    d2a[e] = d2; lmin0 = fminf(lmin0, d2); lmax0 = fmaxf(lmax0, d2);
    dx = x - g1x; dy = y - g1y; dz = z - g1z;
    d2 = dx * dx + dy * dy + dz * dz;
    d2b[e] = d2; lmin1 = fminf(lmin1, d2); lmax1 = fmaxf(lmax1, d2);
  }
#pragma unroll
  for (int off = 32; off >= 1; off >>= 1) {
    lmin0 = fminf(lmin0, __shfl_down(lmin0, off));
    lmax0 = fmaxf(lmax0, __shfl_down(lmax0, off));
    lmin1 = fminf(lmin1, __shfl_down(lmin1, off));
    lmax1 = fmaxf(lmax1, __shfl_down(lmax1, off));
  }
  if (lane == 0) {
    sred[0][wave] = lmin0; sred[1][wave] = lmax0;
    sred[2][wave] = lmin1; sred[3][wave] = lmax1;
  }
  __syncthreads();
  if (t < MPB) {
    float bmin = INFINITY, bmax = 0.0f;
#pragma unroll
    for (int w = 0; w < TT / 64; w++) {
      bmin = fminf(bmin, sred[2 * t][w]);
      bmax = fmaxf(bmax, sred[2 * t + 1][w]);
    }
    sbb[t][0] = bmin;
    sbb[t][1] = bmax;
  }
  __syncthreads();

  // P2: block-uniform bisection for bounds with count(d2 < bound) in [10, CAP]
  float lo0 = sbb[0][0], hi0 = sbb[0][1] + fmaxf(sbb[0][1] * 1e-6f, 1e-30f);
  float lo1 = sbb[1][0], hi1 = sbb[1][1] + fmaxf(sbb[1][1] * 1e-6f, 1e-30f);
  float bound0 = hi0, bound1 = hi1;
  bool done0 = false, done1 = false;
  int buf = 0;
  for (int iter = 0; iter < 48 && !(done0 && done1); iter++) {
    float mid0 = done0 ? bound0 : 0.5f * (lo0 + hi0);
    float mid1 = done1 ? bound1 : 0.5f * (lo1 + hi1);
    int c0 = 0, c1 = 0;
#pragma unroll
    for (int e = 0; e < ELEMS; e++) {
      c0 += (d2a[e] < mid0) ? 1 : 0;
      c1 += (d2b[e] < mid1) ? 1 : 0;
    }
#pragma unroll
    for (int off = 32; off >= 1; off >>= 1) {
      c0 += __shfl_down(c0, off);
      c1 += __shfl_down(c1, off);
    }
    if (lane == 0) { scount[buf][wave][0] = c0; scount[buf][wave][1] = c1; }
    __syncthreads();
    int C0 = 0, C1 = 0;
#pragma unroll
    for (int w = 0; w < TT / 64; w++) { C0 += scount[buf][w][0]; C1 += scount[buf][w][1]; }
    if (!done0) {
      bool collapsed = (mid0 <= lo0) || (mid0 >= hi0);
      if (C0 >= K10 && (C0 <= CAP || collapsed)) { bound0 = mid0; done0 = true; }
      else if (C0 < K10) { if (collapsed) { bound0 = hi0; done0 = true; } else lo0 = mid0; }
      else hi0 = mid0;
    }
    if (!done1) {
      bool collapsed = (mid1 <= lo1) || (mid1 >= hi1);
      if (C1 >= K10 && (C1 <= CAP || collapsed)) { bound1 = mid1; done1 = true; }
      else if (C1 < K10) { if (collapsed) { bound1 = hi1; done1 = true; } else lo1 = mid1; }
      else hi1 = mid1;
    }
    buf ^= 1;
  }

  // P4: collect candidates (wave-aggregated; one LDS atomic per wave per hit)
#pragma unroll
  for (int e = 0; e < ELEMS; e++) {
    int n = t + e * TT;
    bool pa = d2a[e] < bound0;
    unsigned long long mask = __ballot(pa);
    if (mask) {
      int leader = __ffsll((long long)mask) - 1;
      int cnt = __popcll(mask);
      int base = 0;
      if (lane == leader) base = atomicAdd(&scnt[0], cnt);
      base = __shfl(base, leader);
      int pos = base + __popcll(mask & ((1ull << lane) - 1ull));
      if (pa && pos < CAP) { scd[0][pos] = d2a[e]; sci[0][pos] = n; }
    }
    bool pbv = d2b[e] < bound1;
    mask = __ballot(pbv);
    if (mask) {
      int leader = __ffsll((long long)mask) - 1;
      int cnt = __popcll(mask);
      int base = 0;
      if (lane == leader) base = atomicAdd(&scnt[1], cnt);
      base = __shfl(base, leader);
      int pos = base + __popcll(mask & ((1ull << lane) - 1ull));
      if (pbv && pos < CAP) { scd[1][pos] = d2b[e]; sci[1][pos] = n; }
    }
  }
  __syncthreads();
  const int K0 = min(scnt[0], CAP);
  const int K1 = min(scnt[1], CAP);

  // P5: sqrt (matches reference dist exactly), exact rank by (d, idx)
  for (int c = t; c < K0; c += TT) scd[0][c] = sqrtf(scd[0][c]);
  for (int c = t; c < K1; c += TT) scd[1][c] = sqrtf(scd[1][c]);
  __syncthreads();
  for (int c = t; c < K0; c += TT) {
    float dc = scd[0][c]; int ic = sci[0][c];
    int rank = 0;
    for (int o = 0; o < K0; o++) rank += lexless(scd[0][o], sci[0][o], dc, ic) ? 1 : 0;
    if (rank < K10) { soutd[0][rank] = dc; souti[0][rank] = ic; }
  }
  for (int c = t; c < K1; c += TT) {
    float dc = scd[1][c]; int ic = sci[1][c];
    int rank = 0;
    for (int o = 0; o < K1; o++) rank += lexless(scd[1][o], sci[1][o], dc, ic) ? 1 : 0;
    if (rank < K10) { soutd[1][rank] = dc; souti[1][rank] = ic; }
  }
  __syncthreads();

  // epilogue: wave 0 handles m0, wave 1 handles m1
  if (t < MPB * 64) {
    int mw = t >> 6, l = t & 63;
    int m = m0 + mw;
    bool valid = (m < ngt);
    bool pick = (l < K10) && valid && (soutd[mw][l] < COST_THRESH);
    if (pick) atomicMax(&assign[(size_t)bs * NN + souti[mw][l]], m);
    bool matched = __any(pick);
    if (valid && !matched) {
      float a = 0.0f;
      if (l < 5) a = expf(-0.5f * soutd[mw][l]) * (1.0f - pred_scores[(size_t)bs * NN + souti[mw][l]]);
#pragma unroll
      for (int off = 8; off >= 1; off >>= 1) a += __shfl_down(a, off);
      if (l == 0) {
        atomicAdd(per_gt_sum, a * 0.2f);
        atomicOr(&bs_unm[bs], 1);
      }
    }
  }
}

// Fused loss reduction + final combine (last-block ticket).
__global__ void __launch_bounds__(256) loss_final_kernel(
    const float* __restrict__ pred_boxes, const float* __restrict__ pred_scores,
    const float* __restrict__ gt_boxes, const int* __restrict__ assign,
    float* __restrict__ partials, int* __restrict__ done,
    const float* __restrict__ acc, const int* __restrict__ bs_unm,
    const float* __restrict__ wc, const float* __restrict__ wo,
    const float* __restrict__ wu, float* __restrict__ out) {
  int tid = blockIdx.x * blockDim.x + threadIdx.x;
  float lc = 0.0f, spp = 0.0f, spn = 0.0f, np = 0.0f;
  for (int i = tid; i < TOTAL; i += gridDim.x * blockDim.x) {
    int a = assign[i];
    float x = pred_scores[i];
    if (a >= 0) {
      np += 1.0f;
      int b = i / (NS * NN);
      const float* gbp = &gt_boxes[(b * NM + a) * 7];
#pragma unroll
      for (int c = 0; c < 3; c++) {
        float diff = pred_boxes[(size_t)i * 7 + c] - gbp[c];
        float ad = fabsf(diff);
        lc += (ad < 1.0f) ? 0.5f * ad * ad : (ad - 0.5f);
      }
      spp += log1pf(expf(-fabsf(x))) + fmaxf(-x, 0.0f);  // softplus(-x)
    } else {
      spn += log1pf(expf(-fabsf(x))) + fmaxf(x, 0.0f);   // softplus(x)
    }
  }
#pragma unroll
  for (int off = 32; off >= 1; off >>= 1) {
    lc += __shfl_down(lc, off);
    spp += __shfl_down(spp, off);
    spn += __shfl_down(spn, off);
    np += __shfl_down(np, off);
  }
  __shared__ float red[4][4];
  __shared__ int s_last;
  int wave = threadIdx.x >> 6;
  if ((threadIdx.x & 63) == 0) {
    red[wave][0] = lc; red[wave][1] = spp; red[wave][2] = spn; red[wave][3] = np;
  }
  __syncthreads();
  if (threadIdx.x == 0) {
    float o0 = 0, o1 = 0, o2 = 0, o3 = 0;
#pragma unroll
    for (int w = 0; w < 4; w++) { o0 += red[w][0]; o1 += red[w][1]; o2 += red[w][2]; o3 += red[w][3]; }
    float* p = &partials[(size_t)blockIdx.x * 8];
    __hip_atomic_store(&p[0], o0, __ATOMIC_RELAXED, __HIP_MEMORY_SCOPE_AGENT);
    __hip_atomic_store(&p[1], o1, __ATOMIC_RELAXED, __HIP_MEMORY_SCOPE_AGENT);
    __hip_atomic_store(&p[2], o2, __ATOMIC_RELAXED, __HIP_MEMORY_SCOPE_AGENT);
    __hip_atomic_store(&p[3], o3, __ATOMIC_RELAXED, __HIP_MEMORY_SCOPE_AGENT);
    __threadfence();
    int ticket = __hip_atomic_fetch_add(done, 1, __ATOMIC_ACQ_REL, __HIP_MEMORY_SCOPE_AGENT);
    s_last = (ticket == gridDim.x - 1) ? 1 : 0;
  }
  __syncthreads();
  if (s_last) {
    __threadfence();
    const int t = threadIdx.x;
    float l0 = __hip_atomic_load(&partials[t * 8 + 0], __ATOMIC_RELAXED, __HIP_MEMORY_SCOPE_AGENT);
    float l1 = __hip_atomic_load(&partials[t * 8 + 1], __ATOMIC_RELAXED, __HIP_MEMORY_SCOPE_AGENT);
    float l2 = __hip_atomic_load(&partials[t * 8 + 2], __ATOMIC_RELAXED, __HIP_MEMORY_SCOPE_AGENT);
    float l3 = __hip_atomic_load(&partials[t * 8 + 3], __ATOMIC_RELAXED, __HIP_MEMORY_SCOPE_AGENT);
#pragma unroll
    for (int off = 32; off >= 1; off >>= 1) {
      l0 += __shfl_down(l0, off);
      l1 += __shfl_down(l1, off);
      l2 += __shfl_down(l2, off);
      l3 += __shfl_down(l3, off);
    }
    __shared__ float red2[4][4];
    if ((t & 63) == 0) {
      red2[t >> 6][0] = l0; red2[t >> 6][1] = l1; red2[t >> 6][2] = l2; red2[t >> 6][3] = l3;
    }
    __syncthreads();
    if (t == 0) {
      float o0 = 0, o1 = 0, o2 = 0, o3 = 0;
#pragma unroll
      for (int w = 0; w < 4; w++) { o0 += red2[w][0]; o1 += red2[w][1]; o2 += red2[w][2]; o3 += red2[w][3]; }
      int ne = 0;
      for (int i = 0; i < NB * NS; i++) ne += bs_unm[i];
      float n_pos = o3;
      float loss_center = o0 / fmaxf(n_pos * 3.0f, 1.0f);
      float n_neg = (float)TOTAL - n_pos;
      float pw = fminf(10.0f, n_neg / fmaxf(n_pos, 1.0f));
      float loss_obj = (pw * o1 + o2) / (float)TOTAL;
      float loss_unm = acc[0] / fmaxf((float)ne, 1.0f);
      out[0] = loss_center * wc[0] + loss_obj * wo[0] + loss_unm * wu[0];
    }
  }
}

extern "C" void kernel_launch(void* const* d_in, const int* in_sizes, int n_in,
                              void* d_out, int out_size, void* d_ws, size_t ws_size,
                              hipStream_t stream) {
  const float* pred_boxes = (const float*)d_in[0];
  // d_in[1] = pred_classes (unused), d_in[4] = gt_classes (unused), d_in[9] = epoch (unused)
  const float* pred_scores = (const float*)d_in[2];
  const float* gt_boxes = (const float*)d_in[3];
  const int* n_gt = (const int*)d_in[5];
  const float* wc = (const float*)d_in[6];
  const float* wo = (const float*)d_in[7];
  const float* wu = (const float*)d_in[8];
  float* out = (float*)d_out;

  char* ws = (char*)d_ws;
  int* assign = (int*)ws;                                   // TOTAL ints (1 MB)
  float* acc = (float*)(ws + (size_t)TOTAL * 4);            // acc[0] = per_gt_sum
  int* done = (int*)((char*)acc + 64);
  int* bs_unm = (int*)((char*)acc + 128);                   // NB*NS ints
  float* partials = (float*)((char*)acc + 512);             // LOSS_BLOCKS * 8 floats

  prep_kernel<<<256, 256, 0, stream>>>(assign, acc, bs_unm, done);
  topk_kernel<<<NB * NS * (NM / MPB), TT, 0, stream>>>(pred_boxes, pred_scores, gt_boxes,
                                                       n_gt, assign, &acc[0], bs_unm);
  loss_final_kernel<<<LOSS_BLOCKS, 256, 0, stream>>>(pred_boxes, pred_scores, gt_boxes, assign,
                                                     partials, done, acc, bs_unm, wc, wo, wu, out);
}

// Round 9
// 53.626 us; speedup vs baseline: 5.6370x; 5.6370x over previous
//
#include <hip/hip_runtime.h>

#define NB 8
#define NS 4
#define NN 8192
#define NM 50
#define K10 10
#define COST_THRESH 50.0f
#define LOSS_BLOCKS 256
#define CAP 1024               // candidate storage
#define CAP_HI 128             // bisection acceptance upper bound
#define TOTAL (NB * NS * NN)
#define TT 512                 // topk threads
#define ELEMS (NN / TT)        // 16 per thread

__device__ __forceinline__ bool lexless(float d1, int i1, float d2, int i2) {
  // matches jax.lax.top_k ordering on -dist: (dist asc, index asc)
  return (d1 < d2) || (d1 == d2 && i1 < i2);
}

// Clear assign + scalars, pack pred xyz into SoA streams (bit-exact copy).
__global__ void __launch_bounds__(256) prep_kernel(
    const float* __restrict__ pred_boxes, float* __restrict__ packed,
    int* __restrict__ assign, float* __restrict__ acc,
    int* __restrict__ bs_unm, int* __restrict__ done) {
  int i = blockIdx.x * blockDim.x + threadIdx.x;
  for (int j = i; j < TOTAL; j += gridDim.x * blockDim.x) {
    assign[j] = -1;
    packed[j] = pred_boxes[j * 7 + 0];
    packed[TOTAL + j] = pred_boxes[j * 7 + 1];
    packed[2 * TOTAL + j] = pred_boxes[j * 7 + 2];
  }
  if (i == 0) { acc[0] = 0.0f; *done = 0; }
  if (i >= 64 && i < 64 + NB * NS) bs_unm[i - 64] = 0;
}

// One block per (b, s, m): exact top-10 nearest preds by (dist, idx).
// Bound found by block-uniform bisection on d^2 (register compares only —
// no LDS-atomic histogram, no scratch: 16 floats/thread, VGPR-capped 128).
__global__ void __launch_bounds__(TT, 4) topk_kernel(
    const float* __restrict__ packed, const float* __restrict__ pred_scores,
    const float* __restrict__ gt_boxes, const int* __restrict__ n_gt,
    int* __restrict__ assign, float* __restrict__ per_gt_sum,
    int* __restrict__ bs_unm) {
  const int blk = blockIdx.x;      // b*NS*NM + s*NM + m
  const int m = blk % NM;
  const int bs = blk / NM;
  const int b = bs / NS;
  const int t = threadIdx.x;
  const int wave = t >> 6;
  const int lane = t & 63;

  __shared__ float scd[CAP];            // 4 KB
  __shared__ int sci[CAP];              // 4 KB
  __shared__ float sred[2][8];          // {min,max} x 8 waves
  __shared__ float sbb[2];              // bmin, bmax
  __shared__ int scount[2][8];          // bisection partial counts (dbuf)
  __shared__ int scnt;
  __shared__ float soutd[K10];
  __shared__ int souti[K10];

  if (t == 0) scnt = 0;

  const float gx = gt_boxes[(b * NM + m) * 7 + 0];
  const float gy = gt_boxes[(b * NM + m) * 7 + 1];
  const float gz = gt_boxes[(b * NM + m) * 7 + 2];
  const bool valid = (m < n_gt[b]);

  const float4* px4 = (const float4*)(packed + (size_t)bs * NN);
  const float4* py4 = (const float4*)(packed + TOTAL + (size_t)bs * NN);
  const float4* pz4 = (const float4*)(packed + 2 * TOTAL + (size_t)bs * NN);

  // P1: d^2 into registers (16/thread); block min/max
  float d2r[ELEMS];
  float lmin = INFINITY, lmax = 0.0f;
#pragma unroll
  for (int c = 0; c < ELEMS / 4; c++) {
    float4 vx = px4[c * TT + t];
    float4 vy = py4[c * TT + t];
    float4 vz = pz4[c * TT + t];
    float dx, dy, dz;
    dx = vx.x - gx; dy = vy.x - gy; dz = vz.x - gz; d2r[c * 4 + 0] = dx * dx + dy * dy + dz * dz;
    dx = vx.y - gx; dy = vy.y - gy; dz = vz.y - gz; d2r[c * 4 + 1] = dx * dx + dy * dy + dz * dz;
    dx = vx.z - gx; dy = vy.z - gy; dz = vz.z - gz; d2r[c * 4 + 2] = dx * dx + dy * dy + dz * dz;
    dx = vx.w - gx; dy = vy.w - gy; dz = vz.w - gz; d2r[c * 4 + 3] = dx * dx + dy * dy + dz * dz;
#pragma unroll
    for (int j = 0; j < 4; j++) {
      lmin = fminf(lmin, d2r[c * 4 + j]);
      lmax = fmaxf(lmax, d2r[c * 4 + j]);
    }
  }
#pragma unroll
  for (int off = 32; off >= 1; off >>= 1) {
    lmin = fminf(lmin, __shfl_down(lmin, off));
    lmax = fmaxf(lmax, __shfl_down(lmax, off));
  }
  if (lane == 0) { sred[0][wave] = lmin; sred[1][wave] = lmax; }
  __syncthreads();
  if (t == 0) {
    float bmin = INFINITY, bmax = 0.0f;
#pragma unroll
    for (int w = 0; w < TT / 64; w++) {
      bmin = fminf(bmin, sred[0][w]);
      bmax = fmaxf(bmax, sred[1][w]);
    }
    sbb[0] = bmin;
    sbb[1] = bmax;
  }
  __syncthreads();

  // P2: block-uniform bisection for bound with count(d2 < bound) in [10, CAP_HI]
  float lo = sbb[0];
  float hi = sbb[1] * 1.000001f + 1e-30f;
  float bound = hi;
  int buf = 0;
  for (int iter = 0; iter < 32; iter++) {
    float mid = 0.5f * (lo + hi);
    int c = 0;
#pragma unroll
    for (int e = 0; e < ELEMS; e++) c += (d2r[e] < mid) ? 1 : 0;
#pragma unroll
    for (int off = 32; off >= 1; off >>= 1) c += __shfl_down(c, off);
    if (lane == 0) scount[buf][wave] = c;
    __syncthreads();
    int C = 0;
#pragma unroll
    for (int w = 0; w < TT / 64; w++) C += scount[buf][w];
    buf ^= 1;
    bool collapsed = (mid <= lo) || (mid >= hi);
    if (C >= K10 && (C <= CAP_HI || collapsed)) { bound = mid; break; }
    if (collapsed) { bound = hi; break; }   // count(hi) >= 10 always
    if (C < K10) lo = mid; else hi = mid;
  }

  // P4: collect candidates (wave-aggregated; <=1 LDS atomic per wave per e)
#pragma unroll
  for (int e = 0; e < ELEMS; e++) {
    int n = (e < ELEMS ? ((e >> 2) * TT + t) * 4 + (e & 3) : 0);  // matches d2r layout
    bool p = d2r[e] < bound;
    unsigned long long mask = __ballot(p);
    if (mask) {
      int leader = __ffsll((long long)mask) - 1;
      int cnt = __popcll(mask);
      int base = 0;
      if (lane == leader) base = atomicAdd(&scnt, cnt);
      base = __shfl(base, leader);
      int pos = base + __popcll(mask & ((1ull << lane) - 1ull));
      if (p && pos < CAP) { scd[pos] = d2r[e]; sci[pos] = n; }
    }
  }
  __syncthreads();
  const int K = min(scnt, CAP);

  // P5: sqrt candidates (matches reference dist exactly), exact rank by (d, idx)
  for (int c = t; c < K; c += TT) scd[c] = sqrtf(scd[c]);
  __syncthreads();
  for (int c = t; c < K; c += TT) {
    float dc = scd[c];
    int ic = sci[c];
    int rank = 0;
    for (int o = 0; o < K; o++) rank += lexless(scd[o], sci[o], dc, ic) ? 1 : 0;
    if (rank < K10) { soutd[rank] = dc; souti[rank] = ic; }
  }
  __syncthreads();

  // epilogue on wave 0: lanes 0..9 scatter, lanes 0..4 unmatched term
  if (t < 64) {
    bool pick = (t < K10) && valid && (soutd[t] < COST_THRESH);
    if (pick) atomicMax(&assign[(size_t)bs * NN + souti[t]], m);
    bool matched = __any(pick);
    if (valid && !matched) {
      float a = 0.0f;
      if (t < 5) a = expf(-0.5f * soutd[t]) * (1.0f - pred_scores[(size_t)bs * NN + souti[t]]);
#pragma unroll
      for (int off = 8; off >= 1; off >>= 1) a += __shfl_down(a, off);
      if (t == 0) {
        atomicAdd(per_gt_sum, a * 0.2f);
        atomicOr(&bs_unm[bs], 1);
      }
    }
  }
}

// Fused loss reduction + final combine (last-block ticket).
__global__ void __launch_bounds__(256) loss_final_kernel(
    const float* __restrict__ packed, const float* __restrict__ pred_scores,
    const float* __restrict__ gt_boxes, const int* __restrict__ assign,
    float* __restrict__ partials, int* __restrict__ done,
    const float* __restrict__ acc, const int* __restrict__ bs_unm,
    const float* __restrict__ wc, const float* __restrict__ wo,
    const float* __restrict__ wu, float* __restrict__ out) {
  int tid = blockIdx.x * blockDim.x + threadIdx.x;
  float lc = 0.0f, spp = 0.0f, spn = 0.0f, np = 0.0f;
  for (int i = tid; i < TOTAL; i += gridDim.x * blockDim.x) {
    int a = assign[i];
    float x = pred_scores[i];
    if (a >= 0) {
      np += 1.0f;
      int b = i / (NS * NN);
      const float* gbp = &gt_boxes[(b * NM + a) * 7];
#pragma unroll
      for (int c = 0; c < 3; c++) {
        float diff = packed[c * TOTAL + i] - gbp[c];
        float ad = fabsf(diff);
        lc += (ad < 1.0f) ? 0.5f * ad * ad : (ad - 0.5f);
      }
      spp += log1pf(expf(-fabsf(x))) + fmaxf(-x, 0.0f);  // softplus(-x)
    } else {
      spn += log1pf(expf(-fabsf(x))) + fmaxf(x, 0.0f);   // softplus(x)
    }
  }
#pragma unroll
  for (int off = 32; off >= 1; off >>= 1) {
    lc += __shfl_down(lc, off);
    spp += __shfl_down(spp, off);
    spn += __shfl_down(spn, off);
    np += __shfl_down(np, off);
  }
  __shared__ float red[4][4];
  __shared__ int s_last;
  int wave = threadIdx.x >> 6;
  if ((threadIdx.x & 63) == 0) {
    red[wave][0] = lc; red[wave][1] = spp; red[wave][2] = spn; red[wave][3] = np;
  }
  __syncthreads();
  if (threadIdx.x == 0) {
    float o0 = 0, o1 = 0, o2 = 0, o3 = 0;
#pragma unroll
    for (int w = 0; w < 4; w++) { o0 += red[w][0]; o1 += red[w][1]; o2 += red[w][2]; o3 += red[w][3]; }
    float* p = &partials[(size_t)blockIdx.x * 8];
    __hip_atomic_store(&p[0], o0, __ATOMIC_RELAXED, __HIP_MEMORY_SCOPE_AGENT);
    __hip_atomic_store(&p[1], o1, __ATOMIC_RELAXED, __HIP_MEMORY_SCOPE_AGENT);
    __hip_atomic_store(&p[2], o2, __ATOMIC_RELAXED, __HIP_MEMORY_SCOPE_AGENT);
    __hip_atomic_store(&p[3], o3, __ATOMIC_RELAXED, __HIP_MEMORY_SCOPE_AGENT);
    __threadfence();
    int ticket = __hip_atomic_fetch_add(done, 1, __ATOMIC_ACQ_REL, __HIP_MEMORY_SCOPE_AGENT);
    s_last = (ticket == gridDim.x - 1) ? 1 : 0;
  }
  __syncthreads();
  if (s_last) {
    __threadfence();
    const int t = threadIdx.x;
    float l0 = __hip_atomic_load(&partials[t * 8 + 0], __ATOMIC_RELAXED, __HIP_MEMORY_SCOPE_AGENT);
    float l1 = __hip_atomic_load(&partials[t * 8 + 1], __ATOMIC_RELAXED, __HIP_MEMORY_SCOPE_AGENT);
    float l2 = __hip_atomic_load(&partials[t * 8 + 2], __ATOMIC_RELAXED, __HIP_MEMORY_SCOPE_AGENT);
    float l3 = __hip_atomic_load(&partials[t * 8 + 3], __ATOMIC_RELAXED, __HIP_MEMORY_SCOPE_AGENT);
#pragma unroll
    for (int off = 32; off >= 1; off >>= 1) {
      l0 += __shfl_down(l0, off);
      l1 += __shfl_down(l1, off);
      l2 += __shfl_down(l2, off);
      l3 += __shfl_down(l3, off);
    }
    __shared__ float red2[4][4];
    if ((t & 63) == 0) {
      red2[t >> 6][0] = l0; red2[t >> 6][1] = l1; red2[t >> 6][2] = l2; red2[t >> 6][3] = l3;
    }
    __syncthreads();
    if (t == 0) {
      float o0 = 0, o1 = 0, o2 = 0, o3 = 0;
#pragma unroll
      for (int w = 0; w < 4; w++) { o0 += red2[w][0]; o1 += red2[w][1]; o2 += red2[w][2]; o3 += red2[w][3]; }
      int ne = 0;
      for (int i = 0; i < NB * NS; i++) ne += bs_unm[i];
      float n_pos = o3;
      float loss_center = o0 / fmaxf(n_pos * 3.0f, 1.0f);
      float n_neg = (float)TOTAL - n_pos;
      float pw = fminf(10.0f, n_neg / fmaxf(n_pos, 1.0f));
      float loss_obj = (pw * o1 + o2) / (float)TOTAL;
      float loss_unm = acc[0] / fmaxf((float)ne, 1.0f);
      out[0] = loss_center * wc[0] + loss_obj * wo[0] + loss_unm * wu[0];
    }
  }
}

extern "C" void kernel_launch(void* const* d_in, const int* in_sizes, int n_in,
                              void* d_out, int out_size, void* d_ws, size_t ws_size,
                              hipStream_t stream) {
  const float* pred_boxes = (const float*)d_in[0];
  // d_in[1] = pred_classes (unused), d_in[4] = gt_classes (unused), d_in[9] = epoch (unused)
  const float* pred_scores = (const float*)d_in[2];
  const float* gt_boxes = (const float*)d_in[3];
  const int* n_gt = (const int*)d_in[5];
  const float* wc = (const float*)d_in[6];
  const float* wo = (const float*)d_in[7];
  const float* wu = (const float*)d_in[8];
  float* out = (float*)d_out;

  char* ws = (char*)d_ws;
  int* assign = (int*)ws;                                   // TOTAL ints (1 MB)
  float* packed = (float*)(ws + (size_t)TOTAL * 4);         // 3*TOTAL floats (3 MB)
  float* acc = (float*)(ws + (size_t)TOTAL * 16);           // acc[0] = per_gt_sum
  int* done = (int*)((char*)acc + 64);
  int* bs_unm = (int*)((char*)acc + 128);                   // NB*NS ints
  float* partials = (float*)((char*)acc + 512);             // LOSS_BLOCKS * 8 floats

  prep_kernel<<<512, 256, 0, stream>>>(pred_boxes, packed, assign, acc, bs_unm, done);
  topk_kernel<<<NB * NS * NM, TT, 0, stream>>>(packed, pred_scores, gt_boxes,
                                               n_gt, assign, &acc[0], bs_unm);
  loss_final_kernel<<<LOSS_BLOCKS, 256, 0, stream>>>(packed, pred_scores, gt_boxes, assign,
                                                     partials, done, acc, bs_unm, wc, wo, wu, out);
}